// Round 20
// baseline (4573.938 us; speedup 1.0000x reference)
//
#include <hip/hip_runtime.h>

typedef unsigned short u16;
typedef unsigned int u32;
typedef unsigned long long u64;
typedef _Float16 f16;
typedef f16 h2 __attribute__((ext_vector_type(2)));
typedef f16 h4 __attribute__((ext_vector_type(4)));
typedef f16 h8 __attribute__((ext_vector_type(8)));
typedef u16 u16x8 __attribute__((ext_vector_type(8)));
typedef float f32x4 __attribute__((ext_vector_type(4)));
typedef float f32x2 __attribute__((ext_vector_type(2)));

#define B_ 64
#define F_ 128
#define H_ 512
#define S_ 512
#define T_ 96
#define NB 256
#define NT 1024

// ---- workspace byte offsets (r16/r18 layout, audited disjoint) ----
#define FLAG_OFF  0ul          // u32[256] @64B stride           -> 16384
#define HP_OFF    20480ul      // f32 [64][512]                  -> 151552
#define XF_OFF    151552ul     // f32 [64][128]                  -> 184320
#define DEN_OFF   184320ul     // f32 [64][4]                    -> 185344
#define CQ_OFF    185344ul     // u32 [64][4][256] f16x2 c parts -> 447488
#define HNEW_OFF  447488ul     // f32 [2][64][512]               -> 709632
#define WTS_OFF   709632ul     // f16 [2359296]                  -> 5428224
#define ENCP8_OFF 5428224ul    // u8 [64][512][512] fp8 2*(enc@Wa2^T+ba) -> 22205440
#define ENCF8_OFF 22205440ul   // u8 [64][512][512] fp8 enc      -> 38982656
#define ENCL_OFF  38982656ul   // f16 [64*512][512] enc (GEMM A) -> 72537088
// end: 72537088 (~69.2 MiB)

// f16-element offsets inside WTS
#define WA1_E  0        // [512][512]  Wa[:, :512]
#define WA2_E  262144   // [512][512]  Wa[:, 512:]
#define WHH_E  524288   // [1536][512]
#define WC_E   1310720  // [1536][512]  Wih[:, 128:]
#define WX_E   2097152  // [1536][128]  Wih[:, :128]
#define WOUT_E 2293760  // [128][512]
#define WTS_N  2359296

__device__ __forceinline__ float fdot2(h2 a, h2 b, float c) {
#if __has_builtin(__builtin_amdgcn_fdot2)
  return __builtin_amdgcn_fdot2(a, b, c, false);
#else
  return c + (float)a[0] * (float)b[0] + (float)a[1] * (float)b[1];
#endif
}
__device__ __forceinline__ u32 packh2(float a, float b) {
  h2 p; p[0] = (f16)a; p[1] = (f16)b;
  return __builtin_bit_cast(u32, p);
}
__device__ __forceinline__ h2 unpackh2(u32 v) { return __builtin_bit_cast(h2, v); }
__device__ __forceinline__ void xstf(float* p, float v) {
  __hip_atomic_exchange(p, v, __ATOMIC_RELAXED, __HIP_MEMORY_SCOPE_AGENT);
}
__device__ __forceinline__ void xstu(u32* p, u32 v) {
  __hip_atomic_exchange(p, v, __ATOMIC_RELAXED, __HIP_MEMORY_SCOPE_AGENT);
}
__device__ __forceinline__ float aldf(const float* p) {
  return __hip_atomic_load(p, __ATOMIC_RELAXED, __HIP_MEMORY_SCOPE_AGENT);
}
__device__ __forceinline__ u32 aldu(const u32* p) {
  return __hip_atomic_load(p, __ATOMIC_RELAXED, __HIP_MEMORY_SCOPE_AGENT);
}

// ---- fp8 (OCP e4m3fn) helpers; HW builtin preferred, manual fallback keeps
// ---- the same little-endian byte order so pack/decode stay inverses.
__device__ __forceinline__ unsigned char f32_to_fp8(float x) {
#if __has_builtin(__builtin_amdgcn_cvt_pk_fp8_f32)
  int r = __builtin_amdgcn_cvt_pk_fp8_f32(x, 0.f, 0, false);
  return (unsigned char)(r & 0xff);
#else
  unsigned b = __float_as_uint(x);
  unsigned s = (b >> 24) & 0x80u;
  float ax = fabsf(x);
  if (ax >= 448.f) return (unsigned char)(s | 0x7E);
  if (ax < 0.0078125f) {
    int m = (int)(ax * 512.f + 0.5f);
    if (m > 7) m = 7;
    return (unsigned char)(s | m);
  }
  unsigned e = (b >> 23) & 0xFF;
  unsigned mant = (b & 0x7FFFFF) + 0x80000;
  if (mant >> 23) { mant = 0; e += 1; }
  if (e > 135 || (e == 135 && ((mant >> 20) & 7) == 7))
    return (unsigned char)(s | 0x7E);
  return (unsigned char)(s | ((e - 120) << 3) | ((mant >> 20) & 7));
#endif
}
__device__ __forceinline__ float fp8_to_f32_manual(unsigned char v) {
  unsigned s = (unsigned)(v & 0x80) << 24;
  unsigned em = v & 0x7F;
  float mag;
  if ((em >> 3) == 0) mag = (float)(em & 7) * 0.001953125f;
  else mag = __uint_as_float((((em >> 3) + 120) << 23) | ((em & 7) << 20));
  return __uint_as_float(s | __float_as_uint(mag));
}
__device__ __forceinline__ void fp8x8_to_f32(u64 v, float* o) {
#if __has_builtin(__builtin_amdgcn_cvt_pk_f32_fp8)
  unsigned lo = (unsigned)v, hi = (unsigned)(v >> 32);
  f32x2 a = __builtin_amdgcn_cvt_pk_f32_fp8((int)lo, false);
  f32x2 b = __builtin_amdgcn_cvt_pk_f32_fp8((int)lo, true);
  f32x2 c = __builtin_amdgcn_cvt_pk_f32_fp8((int)hi, false);
  f32x2 d = __builtin_amdgcn_cvt_pk_f32_fp8((int)hi, true);
  o[0] = a[0]; o[1] = a[1]; o[2] = b[0]; o[3] = b[1];
  o[4] = c[0]; o[5] = c[1]; o[6] = d[0]; o[7] = d[1];
#else
  #pragma unroll
  for (int k = 0; k < 8; ++k) o[k] = fp8_to_f32_manual((unsigned char)(v >> (8 * k)));
#endif
}
__device__ __forceinline__ u32 pack4fp8(float x, float y, float z, float w) {
#if __has_builtin(__builtin_amdgcn_cvt_pk_fp8_f32)
  int r = __builtin_amdgcn_cvt_pk_fp8_f32(x, y, 0, false);
  r = __builtin_amdgcn_cvt_pk_fp8_f32(z, w, r, true);
  return (u32)r;
#else
  return (u32)f32_to_fp8(x) | ((u32)f32_to_fp8(y) << 8) |
         ((u32)f32_to_fp8(z) << 16) | ((u32)f32_to_fp8(w) << 24);
#endif
}

// Flat all-to-all barrier (r16-proven).
__device__ __forceinline__ void gridbar(u32* flags, unsigned ep) {
  __builtin_amdgcn_s_waitcnt(0);
  __syncthreads();
  const int bid = blockIdx.x, tid = threadIdx.x;
  if (tid == 0)
    __hip_atomic_exchange(flags + bid * 16, ep, __ATOMIC_RELAXED, __HIP_MEMORY_SCOPE_AGENT);
  __syncthreads();                 // own store issued before any poll
  if (tid < 255) {
    u32* pf = flags + (((bid + 1 + tid) & 255) * 16);
    int guard = 0;
    while (__hip_atomic_load(pf, __ATOMIC_RELAXED, __HIP_MEMORY_SCOPE_AGENT) < ep) {
      __builtin_amdgcn_s_sleep(1);
      if (++guard > (1 << 17)) break;
    }
  }
  __syncthreads();
  asm volatile("" ::: "memory");
}

// ---------------- enc f32 -> {f16 linear (GEMM A), fp8 (decoder)} ----------------
__global__ __launch_bounds__(256) void transcode_enc(const float* __restrict__ enc,
                                                     f16* __restrict__ encl,
                                                     unsigned char* __restrict__ encf8) {
  int i = blockIdx.x * 256 + threadIdx.x;
  #pragma unroll
  for (int u = 0; u < 4; ++u) {
    int idx = i + u * 1048576;
    float4 v = ((const float4*)enc)[idx];
    h4 o = {(f16)v.x, (f16)v.y, (f16)v.z, (f16)v.w};
    ((h4*)encl)[idx] = o;
    ((u32*)encf8)[idx] = pack4fp8(v.x, v.y, v.z, v.w);
  }
}

// ---------------- pack all weights to f16 (one-time) ----------------
__global__ __launch_bounds__(256) void pack_weights(
    const float* __restrict__ Wa, const float* __restrict__ Whh,
    const float* __restrict__ Wih, const float* __restrict__ Wout,
    f16* __restrict__ WTS) {
  int i = blockIdx.x * 256 + threadIdx.x;
  if (i >= WTS_N) return;
  float x;
  if (i < WA2_E) {
    int n = i >> 9, k = i & 511;
    x = Wa[(size_t)n * 1024 + k];
  } else if (i < WHH_E) {
    int j = i - WA2_E; int n = j >> 9, k = j & 511;
    x = Wa[(size_t)n * 1024 + 512 + k];
  } else if (i < WC_E) {
    int j = i - WHH_E; int n = j >> 9, k = j & 511;
    x = Whh[(size_t)n * 512 + k];
  } else if (i < WX_E) {
    int j = i - WC_E; int n = j >> 9, k = j & 511;
    x = Wih[(size_t)n * 640 + 128 + k];
  } else if (i < WOUT_E) {
    int j = i - WX_E; int n = j >> 7, k = j & 127;
    x = Wih[(size_t)n * 640 + k];
  } else {
    int j = i - WOUT_E; int n = j >> 9, k = j & 511;
    x = Wout[(size_t)n * 512 + k];
  }
  WTS[i] = (f16)x;
}

// ------- MFMA: ENCP8[m][n] = fp8( 2*(sum_k ENCL[m][k]*WA2[n][k] + ba[n]) ) -------
__global__ __launch_bounds__(256) void mfma_encproj(const u16* __restrict__ Abf,
                                                    const u16* __restrict__ Bbf,
                                                    const float* __restrict__ ba,
                                                    unsigned char* __restrict__ C) {
  __shared__ u16 As[128 * 40];
  __shared__ u16 Bs[128 * 40];
  const int tid = threadIdx.x, lane = tid & 63, w = tid >> 6;
  const int m0 = blockIdx.x << 7, n0 = blockIdx.y << 7;
  const int r0 = lane & 15, kh = lane >> 4;
  f32x4 acc[2][8] = {};
  for (int k0 = 0; k0 < 512; k0 += 32) {
    #pragma unroll
    for (int i = 0; i < 2; ++i) {
      int e = tid + (i << 8);
      int row = e >> 2, g = e & 3;
      *(u16x8*)&As[row * 40 + (g << 3)] =
          *(const u16x8*)(Abf + (size_t)(m0 + row) * 512 + k0 + (g << 3));
      *(u16x8*)&Bs[row * 40 + (g << 3)] =
          *(const u16x8*)(Bbf + (size_t)(n0 + row) * 512 + k0 + (g << 3));
    }
    __syncthreads();
    h8 a[2], bb[8];
    #pragma unroll
    for (int r = 0; r < 2; ++r)
      a[r] = *(const h8*)&As[((w << 5) + (r << 4) + r0) * 40 + (kh << 3)];
    #pragma unroll
    for (int c = 0; c < 8; ++c)
      bb[c] = *(const h8*)&Bs[((c << 4) + r0) * 40 + (kh << 3)];
    #pragma unroll
    for (int r = 0; r < 2; ++r)
      #pragma unroll
      for (int c = 0; c < 8; ++c)
        acc[r][c] = __builtin_amdgcn_mfma_f32_16x16x32_f16(a[r], bb[c], acc[r][c], 0, 0, 0);
    __syncthreads();
  }
  #pragma unroll
  for (int c = 0; c < 8; ++c) {
    int n = n0 + (c << 4) + r0;
    float bav = ba[n];
    #pragma unroll
    for (int r = 0; r < 2; ++r) {
      int mbase = m0 + (w << 5) + (r << 4) + (kh << 2);
      #pragma unroll
      for (int t = 0; t < 4; ++t)
        C[(size_t)(mbase + t) * 512 + n] = f32_to_fp8(2.f * (acc[r][c][t] + bav));
    }
  }
}

struct Params {
  const float *hidden, *dec_input, *Wv, *bih, *bhh, *bout;
  const unsigned char *ENCP8, *ENCF8;
  const f16 *WA1, *WHH, *WC, *WX, *WOUT;
  float *HP, *XF, *DEN, *HNEW;
  u32 *CQ, *flags;
  float *out;
};

__global__ __launch_bounds__(NT, 1) void decoder_phases(Params p) {
  __shared__ __align__(16) float hpL[512];
  __shared__ float cpart[16][8][65];   // per-wave c-partials, conflict-free
  __shared__ float dWL[16];
  __shared__ __align__(16) h2 ch2L[4][256];
  __shared__ __align__(16) h2 hh2L[4][256];
  __shared__ __align__(16) h2 xh2L[4][64];
  __shared__ float hfL[4][32];
  __shared__ float invL[4];
  __shared__ float g1L[384], g2L[384];

  const int bid = blockIdx.x, tid = threadIdx.x;
  const int lane = tid & 63, w = tid >> 6;
  unsigned ep = 0;

  // phase-role constants
  const int ab = bid >> 2, asq = bid & 3;          // A: (batch, s-quarter)
  const int bg = bid >> 4;                         // B/C: 4-batch group
  const int rs = bid & 15;                         // B: h-slice; C: row-slice
  const int hsb = rs * 32;

  float wv2[8]; float wvs = 0.f;
  {
    const float* wp = p.Wv + lane * 8;
    #pragma unroll
    for (int e = 0; e < 8; ++e) { float v = wp[e]; wv2[e] = -2.f * v; wvs += v; }
  }

  // ---- r20: enc operands are STEP-INVARIANT -> load once into registers.
  // Each thread owns 8 ENCP rows + 8 ENCF rows (8B fp8 each) for all 96 steps.
  u64 pv8[8], ev8[8];
  {
    const size_t sbase = ((size_t)ab * 512 + asq * 128 + w * 8) << 9;
    const unsigned char* pb = p.ENCP8 + sbase + lane * 8;
    const unsigned char* eb = p.ENCF8 + sbase + lane * 8;
    #pragma unroll
    for (int i = 0; i < 8; ++i) {
      pv8[i] = *(const u64*)(pb + ((size_t)i << 9));
      ev8[i] = *(const u64*)(eb + ((size_t)i << 9));
    }
  }

  // ================= init =================
  #pragma unroll
  for (int rep = 0; rep < 2; ++rep) {
    int idx = rep * NT + tid;
    int b4 = idx >> 9, i = idx & 511;
    float v = p.hidden[(size_t)(bg * 4 + b4) * 512 + i];
    float vp = __shfl_xor(v, 1);
    if (!(i & 1)) hh2L[b4][i >> 1] = h2{(f16)v, (f16)vp};
  }
  if (rs == 0) {
    #pragma unroll
    for (int rep = 0; rep < 2; ++rep) {
      int idx = rep * NT + tid;
      int b4 = idx >> 9, i = idx & 511;
      xstf(p.HNEW + (size_t)(bg * 4 + b4) * 512 + i,
           p.hidden[(size_t)(bg * 4 + b4) * 512 + i]);
    }
  } else if (rs == 1) {
    if (tid < 512) {
      int b = bg * 4 + (tid >> 7), n = tid & 127;
      xstf(p.XF + b * 128 + n, p.dec_input[b * 128 + n]);
    }
  }
  __syncthreads();
  if (tid < 160) {
    int row = rs * 40 + (tid >> 2), b4 = tid & 3;
    if (row < 512) {
      const f16* wr = p.WA1 + (size_t)row * 512;
      float acc = 0.f;
      #pragma unroll 8
      for (int k4 = 0; k4 < 64; ++k4) {
        h8 hv = *(const h8*)&hh2L[b4][k4 * 4];
        h8 wv = *(const h8*)(wr + k4 * 8);
        const h2 *hq = (const h2*)&hv, *wq = (const h2*)&wv;
        #pragma unroll
        for (int e = 0; e < 4; ++e) acc = fdot2(hq[e], wq[e], acc);
      }
      xstf(p.HP + (size_t)(bg * 4 + b4) * 512 + row, 2.f * acc);
    }
  }
  gridbar(p.flags, ++ep);

  for (int step = 0; step < T_; ++step) {
    const int cur = step & 1, nxt = cur ^ 1;
    float* HNc = p.HNEW + cur * (64 * 512);
    float* HNn = p.HNEW + nxt * (64 * 512);

    // ================= A: scores + exp + c-partials over s-quarter =================
    if (tid < 512) {
      hpL[tid] = aldf(p.HP + (size_t)ab * 512 + tid);
    }
    __syncthreads();
    {
      float hp8[8];
      *(float4*)hp8 = *(const float4*)&hpL[lane * 8];
      *(float4*)(hp8 + 4) = *(const float4*)&hpL[lane * 8 + 4];
      float c8[8] = {};
      float den = 0.f;
      #pragma unroll
      for (int i = 0; i < 8; ++i) {
        float pf[8], ef[8];
        fp8x8_to_f32(pv8[i], pf);
        fp8x8_to_f32(ev8[i], ef);
        float acc = wvs;
        #pragma unroll
        for (int e = 0; e < 8; ++e) {
          float e2 = __expf(hp8[e] + pf[e]);                // e^{2x}
          acc += wv2[e] * __builtin_amdgcn_rcpf(e2 + 1.f);  // wv*(1 - 2/(1+e^2x))
        }
        #pragma unroll
        for (int off = 32; off; off >>= 1) acc += __shfl_xor(acc, off);
        float es = __expf(acc);                          // |score| <= ~11: safe
        den += es;
        #pragma unroll
        for (int e = 0; e < 8; ++e) c8[e] += es * ef[e];
      }
      #pragma unroll
      for (int e = 0; e < 8; ++e) cpart[w][e][lane] = c8[e];   // conflict-free
      if (lane == 0) dWL[w] = den;
    }
    __syncthreads();
    if (tid < 256) {
      int h0 = 2 * tid, h1 = 2 * tid + 1;
      float v0 = 0.f, v1 = 0.f;
      #pragma unroll
      for (int ww = 0; ww < 16; ++ww) {
        v0 += cpart[ww][h0 & 7][h0 >> 3];
        v1 += cpart[ww][h1 & 7][h1 >> 3];
      }
      xstu(p.CQ + (size_t)((ab << 2) | asq) * 256 + tid,
           packh2(v0 * 1.220703125e-4f, v1 * 1.220703125e-4f));   // x 2^-13
    } else if (tid == 256) {
      float d = 0.f;
      #pragma unroll
      for (int i = 0; i < 16; ++i) d += dWL[i];
      xstf(p.DEN + (ab << 2) + asq, d);
    }
    gridbar(p.flags, ++ep);

    // ================= B: gates + h update (4 batches x 32-h slice) =================
    if (tid < 4) {
      float s = 0.f;
      #pragma unroll
      for (int sq = 0; sq < 4; ++sq) s += aldf(p.DEN + ((bg * 4 + tid) << 2) + sq);
      invL[tid] = 8192.f * __builtin_amdgcn_rcpf(s);     // 2^13 / den
    }
    __syncthreads();
    {
      int b4 = tid >> 8, pp = tid & 255;
      float lo = 0.f, hi = 0.f;
      #pragma unroll
      for (int sq = 0; sq < 4; ++sq) {
        h2 v = unpackh2(aldu(p.CQ + (size_t)(((bg * 4 + b4) << 2) | sq) * 256 + pp));
        lo += (float)v[0]; hi += (float)v[1];
      }
      float inv = invL[b4];
      ch2L[b4][pp] = h2{(f16)(lo * inv), (f16)(hi * inv)};
    }
    #pragma unroll
    for (int rep = 0; rep < 2; ++rep) {
      int idx = rep * NT + tid;
      int b4 = idx >> 9, i = idx & 511;
      float v = aldf(HNc + (size_t)(bg * 4 + b4) * 512 + i);
      float vp = __shfl_xor(v, 1);
      if (!(i & 1)) hh2L[b4][i >> 1] = h2{(f16)v, (f16)vp};
      int d = i - hsb;
      if (d >= 0 && d < 32) hfL[b4][d] = v;
    }
    if (tid < 256) {
      int b4 = tid >> 6, n2 = (tid & 63) * 2;
      float x0 = aldf(p.XF + (bg * 4 + b4) * 128 + n2);
      float x1 = aldf(p.XF + (bg * 4 + b4) * 128 + n2 + 1);
      xh2L[b4][n2 >> 1] = h2{(f16)x0, (f16)x1};
    }
    __syncthreads();
    if (tid < 384) {
      int b4 = tid & 3, g = (tid >> 2) % 3, r = tid / 12;
      int j = g * 512 + hsb + r;
      const f16* wc = p.WC + (size_t)j * 512;
      const f16* wh = p.WHH + (size_t)j * 512;
      const f16* wx = p.WX + (size_t)j * 128;
      float gc = 0.f, gh = 0.f, gx = 0.f;
      #pragma unroll 4
      for (int k4 = 0; k4 < 64; ++k4) {
        h8 cv = *(const h8*)&ch2L[b4][k4 * 4];
        h8 hv = *(const h8*)&hh2L[b4][k4 * 4];
        h8 wcv = *(const h8*)(wc + k4 * 8);
        h8 whv = *(const h8*)(wh + k4 * 8);
        const h2 *cq = (const h2*)&cv, *hq = (const h2*)&hv;
        const h2 *wcq = (const h2*)&wcv, *whq = (const h2*)&whv;
        #pragma unroll
        for (int e = 0; e < 4; ++e) {
          gc = fdot2(cq[e], wcq[e], gc);
          gh = fdot2(hq[e], whq[e], gh);
        }
      }
      #pragma unroll
      for (int k4 = 0; k4 < 16; ++k4) {
        h8 xv = *(const h8*)&xh2L[b4][k4 * 4];
        h8 wxv = *(const h8*)(wx + k4 * 8);
        const h2 *xq = (const h2*)&xv, *wxq = (const h2*)&wxv;
        #pragma unroll
        for (int e = 0; e < 4; ++e) gx = fdot2(xq[e], wxq[e], gx);
      }
      g1L[tid] = gc + gx + p.bih[j];
      g2L[tid] = gh + p.bhh[j];
    }
    __syncthreads();
    if (tid < 128) {
      int b4 = tid & 3, r = tid >> 2;
      int i0 = r * 12 + b4;
      float rr = __builtin_amdgcn_rcpf(1.f + __expf(-(g1L[i0] + g2L[i0])));
      float zz = __builtin_amdgcn_rcpf(1.f + __expf(-(g1L[i0 + 4] + g2L[i0 + 4])));
      float narg = g1L[i0 + 8] + rr * g2L[i0 + 8];
      float nn = 1.f - 2.f * __builtin_amdgcn_rcpf(1.f + __expf(2.f * narg));
      float hn = (1.f - zz) * nn + zz * hfL[b4][r];
      xstf(HNn + (size_t)(bg * 4 + b4) * 512 + hsb + r, hn);
    }
    gridbar(p.flags, ++ep);

    // ================= C: hp, out, x from h_new =================
    #pragma unroll
    for (int rep = 0; rep < 2; ++rep) {
      int idx = rep * NT + tid;
      int b4 = idx >> 9, i = idx & 511;
      float v = aldf(HNn + (size_t)(bg * 4 + b4) * 512 + i);
      float vp = __shfl_xor(v, 1);
      if (!(i & 1)) hh2L[b4][i >> 1] = h2{(f16)v, (f16)vp};
    }
    __syncthreads();
    if (tid < 160) {
      int row = rs * 40 + (tid >> 2), b4 = tid & 3;
      const f16* wr = (row < 512) ? p.WA1 + (size_t)row * 512
                                  : p.WOUT + (size_t)(row - 512) * 512;
      float acc = 0.f;
      #pragma unroll 8
      for (int k4 = 0; k4 < 64; ++k4) {
        h8 hv = *(const h8*)&hh2L[b4][k4 * 4];
        h8 wv = *(const h8*)(wr + k4 * 8);
        const h2 *hq = (const h2*)&hv, *wq = (const h2*)&wv;
        #pragma unroll
        for (int e = 0; e < 4; ++e) acc = fdot2(hq[e], wq[e], acc);
      }
      int b = bg * 4 + b4;
      if (row < 512) {
        xstf(p.HP + (size_t)b * 512 + row, 2.f * acc);
      } else {
        int n = row - 512;
        float val = acc + p.bout[n];
        p.out[((size_t)b * T_ + step) * F_ + n] = val;
        xstf(p.XF + b * 128 + n, val);
      }
    }
    gridbar(p.flags, ++ep);
  }
}

extern "C" void kernel_launch(void* const* d_in, const int* in_sizes, int n_in,
                              void* d_out, int out_size, void* d_ws, size_t ws_size,
                              hipStream_t stream) {
  const float* dec_input = (const float*)d_in[0];
  const float* hidden    = (const float*)d_in[1];
  const float* enc       = (const float*)d_in[2];
  // d_in[3] expected_outputs, d_in[4] dec_output_len (fixed 96) unused
  const float* Wa   = (const float*)d_in[5];
  const float* ba   = (const float*)d_in[6];
  const float* Wv   = (const float*)d_in[7];
  // d_in[8] bv cancels in softmax
  const float* Wih  = (const float*)d_in[9];
  const float* bih  = (const float*)d_in[10];
  const float* Whh  = (const float*)d_in[11];
  const float* bhh  = (const float*)d_in[12];
  const float* Wout = (const float*)d_in[13];
  const float* bout = (const float*)d_in[14];

  char* ws = (char*)d_ws;
  f16* WTS  = (f16*)(ws + WTS_OFF);
  unsigned char* ENCP8 = (unsigned char*)(ws + ENCP8_OFF);
  unsigned char* ENCF8 = (unsigned char*)(ws + ENCF8_OFF);
  f16* ENCL = (f16*)(ws + ENCL_OFF);

  Params p;
  p.hidden = hidden; p.dec_input = dec_input; p.Wv = Wv;
  p.bih = bih; p.bhh = bhh; p.bout = bout;
  p.ENCP8 = ENCP8; p.ENCF8 = ENCF8;
  p.WA1 = WTS + WA1_E; p.WHH = WTS + WHH_E; p.WC = WTS + WC_E;
  p.WX = WTS + WX_E; p.WOUT = WTS + WOUT_E;
  p.HP = (float*)(ws + HP_OFF); p.XF = (float*)(ws + XF_OFF);
  p.DEN = (float*)(ws + DEN_OFF); p.HNEW = (float*)(ws + HNEW_OFF);
  p.CQ = (u32*)(ws + CQ_OFF);
  p.flags = (u32*)(ws + FLAG_OFF);
  p.out = (float*)d_out;

  hipMemsetAsync(ws, 0, 20480, stream);   // flag lines
  hipLaunchKernelGGL(transcode_enc, dim3(4096), dim3(256), 0, stream,
                     enc, ENCL, ENCF8);
  hipLaunchKernelGGL(pack_weights, dim3(9216), dim3(256), 0, stream,
                     Wa, Whh, Wih, Wout, WTS);
  hipLaunchKernelGGL(mfma_encproj, dim3(256, 4), dim3(256), 0, stream,
                     (const u16*)ENCL, (const u16*)(WTS + WA2_E), ba, ENCP8);

  void* args[] = {&p};
  hipLaunchCooperativeKernel((void*)decoder_phases, dim3(NB), dim3(NT), args, 0,
                             stream);
}

// Round 21
// 3275.431 us; speedup vs baseline: 1.3964x; 1.3964x over previous
//
#include <hip/hip_runtime.h>

typedef unsigned short u16;
typedef unsigned int u32;
typedef unsigned long long u64;
typedef _Float16 f16;
typedef f16 h2 __attribute__((ext_vector_type(2)));
typedef f16 h4 __attribute__((ext_vector_type(4)));
typedef f16 h8 __attribute__((ext_vector_type(8)));
typedef u16 u16x8 __attribute__((ext_vector_type(8)));
typedef float f32x4 __attribute__((ext_vector_type(4)));
typedef float f32x2 __attribute__((ext_vector_type(2)));

#define B_ 64
#define F_ 128
#define H_ 512
#define S_ 512
#define T_ 96
#define NB 256
#define NT 1024
#define TWOLOG2E 2.885390082f   // 2*log2(e): exp(2x) == exp2(TWOLOG2E*x)

// ---- workspace byte offsets (r16/r18 layout, audited disjoint) ----
#define FLAG_OFF  0ul          // u32[256] @64B stride           -> 16384
#define HP_OFF    20480ul      // f32 [64][512]  (stores 2*log2e * h@Wa1^T)
#define XF_OFF    151552ul     // f32 [64][128]
#define DEN_OFF   184320ul     // f32 [64][4]
#define CQ_OFF    185344ul     // u32 [64][4][256] f16x2 c parts
#define HNEW_OFF  447488ul     // f32 [2][64][512]
#define WTS_OFF   709632ul     // f16 [2359296]
#define ENCP8_OFF 5428224ul    // u8 [64][512][512] fp8 2*log2e*(enc@Wa2^T+ba)
#define ENCF8_OFF 22205440ul   // u8 [64][512][512] fp8 enc
#define ENCL_OFF  38982656ul   // f16 [64*512][512] enc (GEMM A)
// end: 72537088 (~69.2 MiB)

// f16-element offsets inside WTS
#define WA1_E  0        // [512][512]  Wa[:, :512]
#define WA2_E  262144   // [512][512]  Wa[:, 512:]
#define WHH_E  524288   // [1536][512]
#define WC_E   1310720  // [1536][512]  Wih[:, 128:]
#define WX_E   2097152  // [1536][128]  Wih[:, :128]
#define WOUT_E 2293760  // [128][512]
#define WTS_N  2359296

__device__ __forceinline__ float fdot2(h2 a, h2 b, float c) {
#if __has_builtin(__builtin_amdgcn_fdot2)
  return __builtin_amdgcn_fdot2(a, b, c, false);
#else
  return c + (float)a[0] * (float)b[0] + (float)a[1] * (float)b[1];
#endif
}
__device__ __forceinline__ u32 packh2(float a, float b) {
  h2 p; p[0] = (f16)a; p[1] = (f16)b;
  return __builtin_bit_cast(u32, p);
}
__device__ __forceinline__ h2 unpackh2(u32 v) { return __builtin_bit_cast(h2, v); }
__device__ __forceinline__ void xstf(float* p, float v) {
  __hip_atomic_exchange(p, v, __ATOMIC_RELAXED, __HIP_MEMORY_SCOPE_AGENT);
}
__device__ __forceinline__ void xstu(u32* p, u32 v) {
  __hip_atomic_exchange(p, v, __ATOMIC_RELAXED, __HIP_MEMORY_SCOPE_AGENT);
}
__device__ __forceinline__ float aldf(const float* p) {
  return __hip_atomic_load(p, __ATOMIC_RELAXED, __HIP_MEMORY_SCOPE_AGENT);
}
__device__ __forceinline__ u32 aldu(const u32* p) {
  return __hip_atomic_load(p, __ATOMIC_RELAXED, __HIP_MEMORY_SCOPE_AGENT);
}

// ---- fp8 (OCP e4m3fn) helpers; HW builtin preferred, manual fallback keeps
// ---- the same little-endian byte order so pack/decode stay inverses.
__device__ __forceinline__ unsigned char f32_to_fp8(float x) {
#if __has_builtin(__builtin_amdgcn_cvt_pk_fp8_f32)
  int r = __builtin_amdgcn_cvt_pk_fp8_f32(x, 0.f, 0, false);
  return (unsigned char)(r & 0xff);
#else
  unsigned b = __float_as_uint(x);
  unsigned s = (b >> 24) & 0x80u;
  float ax = fabsf(x);
  if (ax >= 448.f) return (unsigned char)(s | 0x7E);
  if (ax < 0.0078125f) {
    int m = (int)(ax * 512.f + 0.5f);
    if (m > 7) m = 7;
    return (unsigned char)(s | m);
  }
  unsigned e = (b >> 23) & 0xFF;
  unsigned mant = (b & 0x7FFFFF) + 0x80000;
  if (mant >> 23) { mant = 0; e += 1; }
  if (e > 135 || (e == 135 && ((mant >> 20) & 7) == 7))
    return (unsigned char)(s | 0x7E);
  return (unsigned char)(s | ((e - 120) << 3) | ((mant >> 20) & 7));
#endif
}
__device__ __forceinline__ float fp8_to_f32_manual(unsigned char v) {
  unsigned s = (unsigned)(v & 0x80) << 24;
  unsigned em = v & 0x7F;
  float mag;
  if ((em >> 3) == 0) mag = (float)(em & 7) * 0.001953125f;
  else mag = __uint_as_float((((em >> 3) + 120) << 23) | ((em & 7) << 20));
  return __uint_as_float(s | __float_as_uint(mag));
}
__device__ __forceinline__ void fp8x8_to_f32(u64 v, float* o) {
#if __has_builtin(__builtin_amdgcn_cvt_pk_f32_fp8)
  unsigned lo = (unsigned)v, hi = (unsigned)(v >> 32);
  f32x2 a = __builtin_amdgcn_cvt_pk_f32_fp8((int)lo, false);
  f32x2 b = __builtin_amdgcn_cvt_pk_f32_fp8((int)lo, true);
  f32x2 c = __builtin_amdgcn_cvt_pk_f32_fp8((int)hi, false);
  f32x2 d = __builtin_amdgcn_cvt_pk_f32_fp8((int)hi, true);
  o[0] = a[0]; o[1] = a[1]; o[2] = b[0]; o[3] = b[1];
  o[4] = c[0]; o[5] = c[1]; o[6] = d[0]; o[7] = d[1];
#else
  #pragma unroll
  for (int k = 0; k < 8; ++k) o[k] = fp8_to_f32_manual((unsigned char)(v >> (8 * k)));
#endif
}
__device__ __forceinline__ u32 pack4fp8(float x, float y, float z, float w) {
#if __has_builtin(__builtin_amdgcn_cvt_pk_fp8_f32)
  int r = __builtin_amdgcn_cvt_pk_fp8_f32(x, y, 0, false);
  r = __builtin_amdgcn_cvt_pk_fp8_f32(z, w, r, true);
  return (u32)r;
#else
  return (u32)f32_to_fp8(x) | ((u32)f32_to_fp8(y) << 8) |
         ((u32)f32_to_fp8(z) << 16) | ((u32)f32_to_fp8(w) << 24);
#endif
}

// Flat all-to-all barrier (r16-proven).
__device__ __forceinline__ void gridbar(u32* flags, unsigned ep) {
  __builtin_amdgcn_s_waitcnt(0);
  __syncthreads();
  const int bid = blockIdx.x, tid = threadIdx.x;
  if (tid == 0)
    __hip_atomic_exchange(flags + bid * 16, ep, __ATOMIC_RELAXED, __HIP_MEMORY_SCOPE_AGENT);
  __syncthreads();                 // own store issued before any poll
  if (tid < 255) {
    u32* pf = flags + (((bid + 1 + tid) & 255) * 16);
    int guard = 0;
    while (__hip_atomic_load(pf, __ATOMIC_RELAXED, __HIP_MEMORY_SCOPE_AGENT) < ep) {
      __builtin_amdgcn_s_sleep(1);
      if (++guard > (1 << 17)) break;
    }
  }
  __syncthreads();
  asm volatile("" ::: "memory");
}

// ---------------- enc f32 -> {f16 linear (GEMM A), fp8 (decoder)} ----------------
__global__ __launch_bounds__(256) void transcode_enc(const float* __restrict__ enc,
                                                     f16* __restrict__ encl,
                                                     unsigned char* __restrict__ encf8) {
  int i = blockIdx.x * 256 + threadIdx.x;
  #pragma unroll
  for (int u = 0; u < 4; ++u) {
    int idx = i + u * 1048576;
    float4 v = ((const float4*)enc)[idx];
    h4 o = {(f16)v.x, (f16)v.y, (f16)v.z, (f16)v.w};
    ((h4*)encl)[idx] = o;
    ((u32*)encf8)[idx] = pack4fp8(v.x, v.y, v.z, v.w);
  }
}

// ---------------- pack all weights to f16 (one-time) ----------------
__global__ __launch_bounds__(256) void pack_weights(
    const float* __restrict__ Wa, const float* __restrict__ Whh,
    const float* __restrict__ Wih, const float* __restrict__ Wout,
    f16* __restrict__ WTS) {
  int i = blockIdx.x * 256 + threadIdx.x;
  if (i >= WTS_N) return;
  float x;
  if (i < WA2_E) {
    int n = i >> 9, k = i & 511;
    x = Wa[(size_t)n * 1024 + k];
  } else if (i < WHH_E) {
    int j = i - WA2_E; int n = j >> 9, k = j & 511;
    x = Wa[(size_t)n * 1024 + 512 + k];
  } else if (i < WC_E) {
    int j = i - WHH_E; int n = j >> 9, k = j & 511;
    x = Whh[(size_t)n * 512 + k];
  } else if (i < WX_E) {
    int j = i - WC_E; int n = j >> 9, k = j & 511;
    x = Wih[(size_t)n * 640 + 128 + k];
  } else if (i < WOUT_E) {
    int j = i - WX_E; int n = j >> 7, k = j & 127;
    x = Wih[(size_t)n * 640 + k];
  } else {
    int j = i - WOUT_E; int n = j >> 9, k = j & 511;
    x = Wout[(size_t)n * 512 + k];
  }
  WTS[i] = (f16)x;
}

// -- MFMA: ENCP8[m][n] = fp8( 2*log2e*(sum_k ENCL[m][k]*WA2[n][k] + ba[n]) ) --
__global__ __launch_bounds__(256) void mfma_encproj(const u16* __restrict__ Abf,
                                                    const u16* __restrict__ Bbf,
                                                    const float* __restrict__ ba,
                                                    unsigned char* __restrict__ C) {
  __shared__ u16 As[128 * 40];
  __shared__ u16 Bs[128 * 40];
  const int tid = threadIdx.x, lane = tid & 63, w = tid >> 6;
  const int m0 = blockIdx.x << 7, n0 = blockIdx.y << 7;
  const int r0 = lane & 15, kh = lane >> 4;
  f32x4 acc[2][8] = {};
  for (int k0 = 0; k0 < 512; k0 += 32) {
    #pragma unroll
    for (int i = 0; i < 2; ++i) {
      int e = tid + (i << 8);
      int row = e >> 2, g = e & 3;
      *(u16x8*)&As[row * 40 + (g << 3)] =
          *(const u16x8*)(Abf + (size_t)(m0 + row) * 512 + k0 + (g << 3));
      *(u16x8*)&Bs[row * 40 + (g << 3)] =
          *(const u16x8*)(Bbf + (size_t)(n0 + row) * 512 + k0 + (g << 3));
    }
    __syncthreads();
    h8 a[2], bb[8];
    #pragma unroll
    for (int r = 0; r < 2; ++r)
      a[r] = *(const h8*)&As[((w << 5) + (r << 4) + r0) * 40 + (kh << 3)];
    #pragma unroll
    for (int c = 0; c < 8; ++c)
      bb[c] = *(const h8*)&Bs[((c << 4) + r0) * 40 + (kh << 3)];
    #pragma unroll
    for (int r = 0; r < 2; ++r)
      #pragma unroll
      for (int c = 0; c < 8; ++c)
        acc[r][c] = __builtin_amdgcn_mfma_f32_16x16x32_f16(a[r], bb[c], acc[r][c], 0, 0, 0);
    __syncthreads();
  }
  #pragma unroll
  for (int c = 0; c < 8; ++c) {
    int n = n0 + (c << 4) + r0;
    float bav = ba[n];
    #pragma unroll
    for (int r = 0; r < 2; ++r) {
      int mbase = m0 + (w << 5) + (r << 4) + (kh << 2);
      #pragma unroll
      for (int t = 0; t < 4; ++t)
        C[(size_t)(mbase + t) * 512 + n] = f32_to_fp8(TWOLOG2E * (acc[r][c][t] + bav));
    }
  }
}

struct Params {
  const float *hidden, *dec_input, *Wv, *bih, *bhh, *bout;
  const unsigned char *ENCP8, *ENCF8;
  const f16 *WA1, *WHH, *WC, *WX, *WOUT;
  float *HP, *XF, *DEN, *HNEW;
  u32 *CQ, *flags;
  float *out;
};

__global__ __launch_bounds__(NT, 1) void decoder_phases(Params p) {
  extern __shared__ __align__(16) unsigned char encpL[];   // 64 KB: pinned ENCP slice
  __shared__ __align__(16) float hpL[512];
  __shared__ float cpart[16][8][65];   // per-wave c-partials, conflict-free
  __shared__ float dWL[16];
  __shared__ __align__(16) h2 ch2L[4][256];
  __shared__ __align__(16) h2 hh2L[4][256];
  __shared__ __align__(16) h2 xh2L[4][64];
  __shared__ float hfL[4][32];
  __shared__ float invL[4];
  __shared__ float g1L[384], g2L[384];

  const int bid = blockIdx.x, tid = threadIdx.x;
  const int lane = tid & 63, w = tid >> 6;
  unsigned ep = 0;

  // phase-role constants
  const int ab = bid >> 2, asq = bid & 3;          // A: (batch, s-quarter)
  const int bg = bid >> 4;                         // B/C: 4-batch group
  const int rs = bid & 15;                         // B: h-slice; C: row-slice
  const int hsb = rs * 32;

  float wv2[8]; float wvs = 0.f;
  {
    const float* wp = p.Wv + lane * 8;
    #pragma unroll
    for (int e = 0; e < 8; ++e) { float v = wp[e]; wv2[e] = -2.f * v; wvs += v; }
  }

  // ---- one-time pin of this block's ENCP fp8 slice (128 s x 512 h) ----
  {
    const float4* gp = (const float4*)(p.ENCP8 + (((size_t)ab * 512 + asq * 128) << 9));
    float4* dp = (float4*)encpL;
    #pragma unroll
    for (int r = 0; r < 4; ++r) dp[tid + r * NT] = gp[tid + r * NT];
  }

  // ================= init =================
  #pragma unroll
  for (int rep = 0; rep < 2; ++rep) {
    int idx = rep * NT + tid;
    int b4 = idx >> 9, i = idx & 511;
    float v = p.hidden[(size_t)(bg * 4 + b4) * 512 + i];
    float vp = __shfl_xor(v, 1);
    if (!(i & 1)) hh2L[b4][i >> 1] = h2{(f16)v, (f16)vp};
  }
  if (rs == 0) {
    #pragma unroll
    for (int rep = 0; rep < 2; ++rep) {
      int idx = rep * NT + tid;
      int b4 = idx >> 9, i = idx & 511;
      xstf(p.HNEW + (size_t)(bg * 4 + b4) * 512 + i,
           p.hidden[(size_t)(bg * 4 + b4) * 512 + i]);
    }
  } else if (rs == 1) {
    if (tid < 512) {
      int b = bg * 4 + (tid >> 7), n = tid & 127;
      xstf(p.XF + b * 128 + n, p.dec_input[b * 128 + n]);
    }
  }
  __syncthreads();
  if (tid < 160) {
    int row = rs * 40 + (tid >> 2), b4 = tid & 3;
    if (row < 512) {
      const f16* wr = p.WA1 + (size_t)row * 512;
      float acc = 0.f;
      #pragma unroll 8
      for (int k4 = 0; k4 < 64; ++k4) {
        h8 hv = *(const h8*)&hh2L[b4][k4 * 4];
        h8 wv = *(const h8*)(wr + k4 * 8);
        const h2 *hq = (const h2*)&hv, *wq = (const h2*)&wv;
        #pragma unroll
        for (int e = 0; e < 4; ++e) acc = fdot2(hq[e], wq[e], acc);
      }
      xstf(p.HP + (size_t)(bg * 4 + b4) * 512 + row, TWOLOG2E * acc);
    }
  }
  gridbar(p.flags, ++ep);

  for (int step = 0; step < T_; ++step) {
    const int cur = step & 1, nxt = cur ^ 1;
    float* HNc = p.HNEW + cur * (64 * 512);
    float* HNn = p.HNEW + nxt * (64 * 512);

    // ================= A: scores + exp + c-partials over s-quarter =================
    if (tid < 512) {
      hpL[tid] = aldf(p.HP + (size_t)ab * 512 + tid);
    }
    __syncthreads();
    {
      float hp8[8];
      *(float4*)hp8 = *(const float4*)&hpL[lane * 8];
      *(float4*)(hp8 + 4) = *(const float4*)&hpL[lane * 8 + 4];
      const size_t sbase = (size_t)ab * 512 + asq * 128 + w * 8;
      // ENCP read from LDS (pinned); ENCF streamed with transient preload.
      const unsigned char* pbL = encpL + ((size_t)(w * 8) << 9) + lane * 8;
      const unsigned char* eb = p.ENCF8 + (sbase << 9) + lane * 8;
      u64 ev8[8];
      #pragma unroll
      for (int i = 0; i < 8; ++i)
        ev8[i] = *(const u64*)(eb + ((size_t)i << 9));
      float c8[8] = {};
      float den = 0.f;
      #pragma unroll
      for (int i = 0; i < 8; ++i) {
        u64 pv = *(const u64*)(pbL + ((size_t)i << 9));
        float pf[8], ef[8];
        fp8x8_to_f32(pv, pf);
        fp8x8_to_f32(ev8[i], ef);
        float acc = wvs;
        #pragma unroll
        for (int e = 0; e < 8; ++e) {
          float e2 = exp2f(hp8[e] + pf[e]);                 // args pre-scaled by 2*log2e
          acc += wv2[e] * __builtin_amdgcn_rcpf(e2 + 1.f);  // wv*(1 - 2/(1+e^2x))
        }
        #pragma unroll
        for (int off = 32; off; off >>= 1) acc += __shfl_xor(acc, off);
        float es = __expf(acc);                          // |score| <= ~11: safe
        den += es;
        #pragma unroll
        for (int e = 0; e < 8; ++e) c8[e] += es * ef[e];
      }
      #pragma unroll
      for (int e = 0; e < 8; ++e) cpart[w][e][lane] = c8[e];   // conflict-free
      if (lane == 0) dWL[w] = den;
    }
    __syncthreads();
    if (tid < 256) {
      int h0 = 2 * tid, h1 = 2 * tid + 1;
      float v0 = 0.f, v1 = 0.f;
      #pragma unroll
      for (int ww = 0; ww < 16; ++ww) {
        v0 += cpart[ww][h0 & 7][h0 >> 3];
        v1 += cpart[ww][h1 & 7][h1 >> 3];
      }
      xstu(p.CQ + (size_t)((ab << 2) | asq) * 256 + tid,
           packh2(v0 * 1.220703125e-4f, v1 * 1.220703125e-4f));   // x 2^-13
    } else if (tid == 256) {
      float d = 0.f;
      #pragma unroll
      for (int i = 0; i < 16; ++i) d += dWL[i];
      xstf(p.DEN + (ab << 2) + asq, d);
    }
    gridbar(p.flags, ++ep);

    // ================= B: gates + h update (4 batches x 32-h slice) =================
    if (tid < 4) {
      float s = 0.f;
      #pragma unroll
      for (int sq = 0; sq < 4; ++sq) s += aldf(p.DEN + ((bg * 4 + tid) << 2) + sq);
      invL[tid] = 8192.f * __builtin_amdgcn_rcpf(s);     // 2^13 / den
    }
    __syncthreads();
    {
      int b4 = tid >> 8, pp = tid & 255;
      float lo = 0.f, hi = 0.f;
      #pragma unroll
      for (int sq = 0; sq < 4; ++sq) {
        h2 v = unpackh2(aldu(p.CQ + (size_t)(((bg * 4 + b4) << 2) | sq) * 256 + pp));
        lo += (float)v[0]; hi += (float)v[1];
      }
      float inv = invL[b4];
      ch2L[b4][pp] = h2{(f16)(lo * inv), (f16)(hi * inv)};
    }
    #pragma unroll
    for (int rep = 0; rep < 2; ++rep) {
      int idx = rep * NT + tid;
      int b4 = idx >> 9, i = idx & 511;
      float v = aldf(HNc + (size_t)(bg * 4 + b4) * 512 + i);
      float vp = __shfl_xor(v, 1);
      if (!(i & 1)) hh2L[b4][i >> 1] = h2{(f16)v, (f16)vp};
      int d = i - hsb;
      if (d >= 0 && d < 32) hfL[b4][d] = v;
    }
    if (tid < 256) {
      int b4 = tid >> 6, n2 = (tid & 63) * 2;
      float x0 = aldf(p.XF + (bg * 4 + b4) * 128 + n2);
      float x1 = aldf(p.XF + (bg * 4 + b4) * 128 + n2 + 1);
      xh2L[b4][n2 >> 1] = h2{(f16)x0, (f16)x1};
    }
    __syncthreads();
    if (tid < 384) {
      int b4 = tid & 3, g = (tid >> 2) % 3, r = tid / 12;
      int j = g * 512 + hsb + r;
      const f16* wc = p.WC + (size_t)j * 512;
      const f16* wh = p.WHH + (size_t)j * 512;
      const f16* wx = p.WX + (size_t)j * 128;
      float gc = 0.f, gh = 0.f, gx = 0.f;
      #pragma unroll 4
      for (int k4 = 0; k4 < 64; ++k4) {
        h8 cv = *(const h8*)&ch2L[b4][k4 * 4];
        h8 hv = *(const h8*)&hh2L[b4][k4 * 4];
        h8 wcv = *(const h8*)(wc + k4 * 8);
        h8 whv = *(const h8*)(wh + k4 * 8);
        const h2 *cq = (const h2*)&cv, *hq = (const h2*)&hv;
        const h2 *wcq = (const h2*)&wcv, *whq = (const h2*)&whv;
        #pragma unroll
        for (int e = 0; e < 4; ++e) {
          gc = fdot2(cq[e], wcq[e], gc);
          gh = fdot2(hq[e], whq[e], gh);
        }
      }
      #pragma unroll
      for (int k4 = 0; k4 < 16; ++k4) {
        h8 xv = *(const h8*)&xh2L[b4][k4 * 4];
        h8 wxv = *(const h8*)(wx + k4 * 8);
        const h2 *xq = (const h2*)&xv, *wxq = (const h2*)&wxv;
        #pragma unroll
        for (int e = 0; e < 4; ++e) gx = fdot2(xq[e], wxq[e], gx);
      }
      g1L[tid] = gc + gx + p.bih[j];
      g2L[tid] = gh + p.bhh[j];
    }
    __syncthreads();
    if (tid < 128) {
      int b4 = tid & 3, r = tid >> 2;
      int i0 = r * 12 + b4;
      float rr = __builtin_amdgcn_rcpf(1.f + __expf(-(g1L[i0] + g2L[i0])));
      float zz = __builtin_amdgcn_rcpf(1.f + __expf(-(g1L[i0 + 4] + g2L[i0 + 4])));
      float narg = g1L[i0 + 8] + rr * g2L[i0 + 8];
      float nn = 1.f - 2.f * __builtin_amdgcn_rcpf(1.f + __expf(2.f * narg));
      float hn = (1.f - zz) * nn + zz * hfL[b4][r];
      xstf(HNn + (size_t)(bg * 4 + b4) * 512 + hsb + r, hn);
    }
    gridbar(p.flags, ++ep);

    // ================= C: hp, out, x from h_new =================
    #pragma unroll
    for (int rep = 0; rep < 2; ++rep) {
      int idx = rep * NT + tid;
      int b4 = idx >> 9, i = idx & 511;
      float v = aldf(HNn + (size_t)(bg * 4 + b4) * 512 + i);
      float vp = __shfl_xor(v, 1);
      if (!(i & 1)) hh2L[b4][i >> 1] = h2{(f16)v, (f16)vp};
    }
    __syncthreads();
    if (tid < 160) {
      int row = rs * 40 + (tid >> 2), b4 = tid & 3;
      const f16* wr = (row < 512) ? p.WA1 + (size_t)row * 512
                                  : p.WOUT + (size_t)(row - 512) * 512;
      float acc = 0.f;
      #pragma unroll 8
      for (int k4 = 0; k4 < 64; ++k4) {
        h8 hv = *(const h8*)&hh2L[b4][k4 * 4];
        h8 wv = *(const h8*)(wr + k4 * 8);
        const h2 *hq = (const h2*)&hv, *wq = (const h2*)&wv;
        #pragma unroll
        for (int e = 0; e < 4; ++e) acc = fdot2(hq[e], wq[e], acc);
      }
      int b = bg * 4 + b4;
      if (row < 512) {
        xstf(p.HP + (size_t)b * 512 + row, TWOLOG2E * acc);
      } else {
        int n = row - 512;
        float val = acc + p.bout[n];
        p.out[((size_t)b * T_ + step) * F_ + n] = val;
        xstf(p.XF + b * 128 + n, val);
      }
    }
    gridbar(p.flags, ++ep);
  }
}

extern "C" void kernel_launch(void* const* d_in, const int* in_sizes, int n_in,
                              void* d_out, int out_size, void* d_ws, size_t ws_size,
                              hipStream_t stream) {
  const float* dec_input = (const float*)d_in[0];
  const float* hidden    = (const float*)d_in[1];
  const float* enc       = (const float*)d_in[2];
  // d_in[3] expected_outputs, d_in[4] dec_output_len (fixed 96) unused
  const float* Wa   = (const float*)d_in[5];
  const float* ba   = (const float*)d_in[6];
  const float* Wv   = (const float*)d_in[7];
  // d_in[8] bv cancels in softmax
  const float* Wih  = (const float*)d_in[9];
  const float* bih  = (const float*)d_in[10];
  const float* Whh  = (const float*)d_in[11];
  const float* bhh  = (const float*)d_in[12];
  const float* Wout = (const float*)d_in[13];
  const float* bout = (const float*)d_in[14];

  char* ws = (char*)d_ws;
  f16* WTS  = (f16*)(ws + WTS_OFF);
  unsigned char* ENCP8 = (unsigned char*)(ws + ENCP8_OFF);
  unsigned char* ENCF8 = (unsigned char*)(ws + ENCF8_OFF);
  f16* ENCL = (f16*)(ws + ENCL_OFF);

  Params p;
  p.hidden = hidden; p.dec_input = dec_input; p.Wv = Wv;
  p.bih = bih; p.bhh = bhh; p.bout = bout;
  p.ENCP8 = ENCP8; p.ENCF8 = ENCF8;
  p.WA1 = WTS + WA1_E; p.WHH = WTS + WHH_E; p.WC = WTS + WC_E;
  p.WX = WTS + WX_E; p.WOUT = WTS + WOUT_E;
  p.HP = (float*)(ws + HP_OFF); p.XF = (float*)(ws + XF_OFF);
  p.DEN = (float*)(ws + DEN_OFF); p.HNEW = (float*)(ws + HNEW_OFF);
  p.CQ = (u32*)(ws + CQ_OFF);
  p.flags = (u32*)(ws + FLAG_OFF);
  p.out = (float*)d_out;

  hipMemsetAsync(ws, 0, 20480, stream);   // flag lines
  hipLaunchKernelGGL(transcode_enc, dim3(4096), dim3(256), 0, stream,
                     enc, ENCL, ENCF8);
  hipLaunchKernelGGL(pack_weights, dim3(9216), dim3(256), 0, stream,
                     Wa, Whh, Wih, Wout, WTS);
  hipLaunchKernelGGL(mfma_encproj, dim3(256, 4), dim3(256), 0, stream,
                     (const u16*)ENCL, (const u16*)(WTS + WA2_E), ba, ENCP8);

  void* args[] = {&p};
  hipLaunchCooperativeKernel((void*)decoder_phases, dim3(NB), dim3(NT), args,
                             65536, stream);
}

// Round 22
// 2792.184 us; speedup vs baseline: 1.6381x; 1.1731x over previous
//
#include <hip/hip_runtime.h>

typedef unsigned short u16;
typedef unsigned int u32;
typedef unsigned long long u64;
typedef _Float16 f16;
typedef f16 h2 __attribute__((ext_vector_type(2)));
typedef f16 h4 __attribute__((ext_vector_type(4)));
typedef f16 h8 __attribute__((ext_vector_type(8)));
typedef u16 u16x8 __attribute__((ext_vector_type(8)));
typedef float f32x4 __attribute__((ext_vector_type(4)));
typedef float f32x2 __attribute__((ext_vector_type(2)));

#define B_ 64
#define F_ 128
#define H_ 512
#define S_ 512
#define T_ 96
#define NB 256
#define NT 1024

// ---- workspace byte offsets (r18 layout, audited disjoint) ----
#define FLAG_OFF  0ul          // u32[256] @64B stride           -> 16384
#define HP_OFF    20480ul      // f32 [64][512]
#define XF_OFF    151552ul     // f32 [64][128]
#define DEN_OFF   184320ul     // f32 [64][4]
#define CQ_OFF    185344ul     // u32 [64][4][256] f16x2 c parts
#define HNEW_OFF  447488ul     // f32 [2][64][512]
#define WTS_OFF   709632ul     // f16 [2359296]
#define ENCP8_OFF 5428224ul    // u8 [64][512][512] fp8 2*(enc@Wa2^T+ba)
#define ENCF8_OFF 22205440ul   // u8 [64][512][512] fp8 enc
#define ENCL_OFF  38982656ul   // f16 [64*512][512] enc (GEMM A)
// end: 72537088 (~69.2 MiB)

// f16-element offsets inside WTS
#define WA1_E  0        // [512][512]  Wa[:, :512]
#define WA2_E  262144   // [512][512]  Wa[:, 512:]
#define WHH_E  524288   // [1536][512]
#define WC_E   1310720  // [1536][512]  Wih[:, 128:]
#define WX_E   2097152  // [1536][128]  Wih[:, :128]
#define WOUT_E 2293760  // [128][512]
#define WTS_N  2359296

__device__ __forceinline__ float fdot2(h2 a, h2 b, float c) {
#if __has_builtin(__builtin_amdgcn_fdot2)
  return __builtin_amdgcn_fdot2(a, b, c, false);
#else
  return c + (float)a[0] * (float)b[0] + (float)a[1] * (float)b[1];
#endif
}
__device__ __forceinline__ u32 packh2(float a, float b) {
  h2 p; p[0] = (f16)a; p[1] = (f16)b;
  return __builtin_bit_cast(u32, p);
}
__device__ __forceinline__ h2 unpackh2(u32 v) { return __builtin_bit_cast(h2, v); }
__device__ __forceinline__ void xstf(float* p, float v) {
  __hip_atomic_exchange(p, v, __ATOMIC_RELAXED, __HIP_MEMORY_SCOPE_AGENT);
}
__device__ __forceinline__ void xstu(u32* p, u32 v) {
  __hip_atomic_exchange(p, v, __ATOMIC_RELAXED, __HIP_MEMORY_SCOPE_AGENT);
}
__device__ __forceinline__ float aldf(const float* p) {
  return __hip_atomic_load(p, __ATOMIC_RELAXED, __HIP_MEMORY_SCOPE_AGENT);
}
__device__ __forceinline__ u32 aldu(const u32* p) {
  return __hip_atomic_load(p, __ATOMIC_RELAXED, __HIP_MEMORY_SCOPE_AGENT);
}

// ---- fp8 (OCP e4m3fn) helpers; HW builtin preferred, manual fallback keeps
// ---- the same little-endian byte order so pack/decode stay inverses.
__device__ __forceinline__ unsigned char f32_to_fp8(float x) {
#if __has_builtin(__builtin_amdgcn_cvt_pk_fp8_f32)
  int r = __builtin_amdgcn_cvt_pk_fp8_f32(x, 0.f, 0, false);
  return (unsigned char)(r & 0xff);
#else
  unsigned b = __float_as_uint(x);
  unsigned s = (b >> 24) & 0x80u;
  float ax = fabsf(x);
  if (ax >= 448.f) return (unsigned char)(s | 0x7E);
  if (ax < 0.0078125f) {
    int m = (int)(ax * 512.f + 0.5f);
    if (m > 7) m = 7;
    return (unsigned char)(s | m);
  }
  unsigned e = (b >> 23) & 0xFF;
  unsigned mant = (b & 0x7FFFFF) + 0x80000;
  if (mant >> 23) { mant = 0; e += 1; }
  if (e > 135 || (e == 135 && ((mant >> 20) & 7) == 7))
    return (unsigned char)(s | 0x7E);
  return (unsigned char)(s | ((e - 120) << 3) | ((mant >> 20) & 7));
#endif
}
__device__ __forceinline__ float fp8_to_f32_manual(unsigned char v) {
  unsigned s = (unsigned)(v & 0x80) << 24;
  unsigned em = v & 0x7F;
  float mag;
  if ((em >> 3) == 0) mag = (float)(em & 7) * 0.001953125f;
  else mag = __uint_as_float((((em >> 3) + 120) << 23) | ((em & 7) << 20));
  return __uint_as_float(s | __float_as_uint(mag));
}
__device__ __forceinline__ void fp8x8_to_f32(u64 v, float* o) {
#if __has_builtin(__builtin_amdgcn_cvt_pk_f32_fp8)
  unsigned lo = (unsigned)v, hi = (unsigned)(v >> 32);
  f32x2 a = __builtin_amdgcn_cvt_pk_f32_fp8((int)lo, false);
  f32x2 b = __builtin_amdgcn_cvt_pk_f32_fp8((int)lo, true);
  f32x2 c = __builtin_amdgcn_cvt_pk_f32_fp8((int)hi, false);
  f32x2 d = __builtin_amdgcn_cvt_pk_f32_fp8((int)hi, true);
  o[0] = a[0]; o[1] = a[1]; o[2] = b[0]; o[3] = b[1];
  o[4] = c[0]; o[5] = c[1]; o[6] = d[0]; o[7] = d[1];
#else
  #pragma unroll
  for (int k = 0; k < 8; ++k) o[k] = fp8_to_f32_manual((unsigned char)(v >> (8 * k)));
#endif
}
__device__ __forceinline__ u32 pack4fp8(float x, float y, float z, float w) {
#if __has_builtin(__builtin_amdgcn_cvt_pk_fp8_f32)
  int r = __builtin_amdgcn_cvt_pk_fp8_f32(x, y, 0, false);
  r = __builtin_amdgcn_cvt_pk_fp8_f32(z, w, r, true);
  return (u32)r;
#else
  return (u32)f32_to_fp8(x) | ((u32)f32_to_fp8(y) << 8) |
         ((u32)f32_to_fp8(z) << 16) | ((u32)f32_to_fp8(w) << 24);
#endif
}

// r22: 16-block GROUP barrier. The dependency graph is closed within each
// group of 16 consecutive blocks (batches 4bg..4bg+3 <-> bids 16bg..16bg+15):
// HP/CQ/DEN/XF/HNEW are all batch-group-partitioned. Store own flag, then
// 15 threads poll the 15 peers in parallel. Groups drift independently.
__device__ __forceinline__ void groupbar(u32* flags, unsigned ep) {
  __builtin_amdgcn_s_waitcnt(0);   // drain exchange-RMWs (acked at MALL)
  __syncthreads();
  const int bid = blockIdx.x, tid = threadIdx.x;
  const int g0 = bid & ~15;
  if (tid == 0)
    __hip_atomic_exchange(flags + bid * 16, ep, __ATOMIC_RELAXED, __HIP_MEMORY_SCOPE_AGENT);
  __syncthreads();                 // own store issued before any poll
  if (tid < 15) {
    int peer = g0 + (((bid - g0) + 1 + tid) & 15);
    u32* pf = flags + peer * 16;
    int guard = 0;
    while (__hip_atomic_load(pf, __ATOMIC_RELAXED, __HIP_MEMORY_SCOPE_AGENT) < ep) {
      __builtin_amdgcn_s_sleep(1);
      if (++guard > (1 << 17)) break;
    }
  }
  __syncthreads();
  asm volatile("" ::: "memory");
}

// ---------------- enc f32 -> {f16 linear (GEMM A), fp8 (decoder)} ----------------
__global__ __launch_bounds__(256) void transcode_enc(const float* __restrict__ enc,
                                                     f16* __restrict__ encl,
                                                     unsigned char* __restrict__ encf8) {
  int i = blockIdx.x * 256 + threadIdx.x;
  #pragma unroll
  for (int u = 0; u < 4; ++u) {
    int idx = i + u * 1048576;
    float4 v = ((const float4*)enc)[idx];
    h4 o = {(f16)v.x, (f16)v.y, (f16)v.z, (f16)v.w};
    ((h4*)encl)[idx] = o;
    ((u32*)encf8)[idx] = pack4fp8(v.x, v.y, v.z, v.w);
  }
}

// ---------------- pack all weights to f16 (one-time) ----------------
__global__ __launch_bounds__(256) void pack_weights(
    const float* __restrict__ Wa, const float* __restrict__ Whh,
    const float* __restrict__ Wih, const float* __restrict__ Wout,
    f16* __restrict__ WTS) {
  int i = blockIdx.x * 256 + threadIdx.x;
  if (i >= WTS_N) return;
  float x;
  if (i < WA2_E) {
    int n = i >> 9, k = i & 511;
    x = Wa[(size_t)n * 1024 + k];
  } else if (i < WHH_E) {
    int j = i - WA2_E; int n = j >> 9, k = j & 511;
    x = Wa[(size_t)n * 1024 + 512 + k];
  } else if (i < WC_E) {
    int j = i - WHH_E; int n = j >> 9, k = j & 511;
    x = Whh[(size_t)n * 512 + k];
  } else if (i < WX_E) {
    int j = i - WC_E; int n = j >> 9, k = j & 511;
    x = Wih[(size_t)n * 640 + 128 + k];
  } else if (i < WOUT_E) {
    int j = i - WX_E; int n = j >> 7, k = j & 127;
    x = Wih[(size_t)n * 640 + k];
  } else {
    int j = i - WOUT_E; int n = j >> 9, k = j & 511;
    x = Wout[(size_t)n * 512 + k];
  }
  WTS[i] = (f16)x;
}

// ------- MFMA: ENCP8[m][n] = fp8( 2*(sum_k ENCL[m][k]*WA2[n][k] + ba[n]) ) -------
__global__ __launch_bounds__(256) void mfma_encproj(const u16* __restrict__ Abf,
                                                    const u16* __restrict__ Bbf,
                                                    const float* __restrict__ ba,
                                                    unsigned char* __restrict__ C) {
  __shared__ u16 As[128 * 40];
  __shared__ u16 Bs[128 * 40];
  const int tid = threadIdx.x, lane = tid & 63, w = tid >> 6;
  const int m0 = blockIdx.x << 7, n0 = blockIdx.y << 7;
  const int r0 = lane & 15, kh = lane >> 4;
  f32x4 acc[2][8] = {};
  for (int k0 = 0; k0 < 512; k0 += 32) {
    #pragma unroll
    for (int i = 0; i < 2; ++i) {
      int e = tid + (i << 8);
      int row = e >> 2, g = e & 3;
      *(u16x8*)&As[row * 40 + (g << 3)] =
          *(const u16x8*)(Abf + (size_t)(m0 + row) * 512 + k0 + (g << 3));
      *(u16x8*)&Bs[row * 40 + (g << 3)] =
          *(const u16x8*)(Bbf + (size_t)(n0 + row) * 512 + k0 + (g << 3));
    }
    __syncthreads();
    h8 a[2], bb[8];
    #pragma unroll
    for (int r = 0; r < 2; ++r)
      a[r] = *(const h8*)&As[((w << 5) + (r << 4) + r0) * 40 + (kh << 3)];
    #pragma unroll
    for (int c = 0; c < 8; ++c)
      bb[c] = *(const h8*)&Bs[((c << 4) + r0) * 40 + (kh << 3)];
    #pragma unroll
    for (int r = 0; r < 2; ++r)
      #pragma unroll
      for (int c = 0; c < 8; ++c)
        acc[r][c] = __builtin_amdgcn_mfma_f32_16x16x32_f16(a[r], bb[c], acc[r][c], 0, 0, 0);
    __syncthreads();
  }
  #pragma unroll
  for (int c = 0; c < 8; ++c) {
    int n = n0 + (c << 4) + r0;
    float bav = ba[n];
    #pragma unroll
    for (int r = 0; r < 2; ++r) {
      int mbase = m0 + (w << 5) + (r << 4) + (kh << 2);
      #pragma unroll
      for (int t = 0; t < 4; ++t)
        C[(size_t)(mbase + t) * 512 + n] = f32_to_fp8(2.f * (acc[r][c][t] + bav));
    }
  }
}

struct Params {
  const float *hidden, *dec_input, *Wv, *bih, *bhh, *bout;
  const unsigned char *ENCP8, *ENCF8;
  const f16 *WA1, *WHH, *WC, *WX, *WOUT;
  float *HP, *XF, *DEN, *HNEW;
  u32 *CQ, *flags;
  float *out;
};

__global__ __launch_bounds__(NT, 1) void decoder_phases(Params p) {
  extern __shared__ __align__(16) unsigned char encpL[];   // 64 KB: pinned ENCP slice
  __shared__ __align__(16) float hpL[512];
  __shared__ float cpart[16][8][65];   // per-wave c-partials, conflict-free
  __shared__ float dWL[16];
  __shared__ __align__(16) h2 ch2L[4][256];
  __shared__ __align__(16) h2 hh2L[4][256];
  __shared__ __align__(16) h2 xh2L[4][64];
  __shared__ float hfL[4][32];
  __shared__ float invL[4];
  __shared__ float g1L[384], g2L[384];

  const int bid = blockIdx.x, tid = threadIdx.x;
  const int lane = tid & 63, w = tid >> 6;
  unsigned ep = 0;

  // phase-role constants
  const int ab = bid >> 2, asq = bid & 3;          // A: (batch, s-quarter)
  const int bg = bid >> 4;                         // B/C: 4-batch group
  const int rs = bid & 15;                         // B: h-slice; C: row-slice
  const int hsb = rs * 32;

  float wv2[8]; float wvs = 0.f;
  {
    const float* wp = p.Wv + lane * 8;
    #pragma unroll
    for (int e = 0; e < 8; ++e) { float v = wp[e]; wv2[e] = -2.f * v; wvs += v; }
  }

  // ---- one-time pin of this block's ENCP fp8 slice (128 s x 512 h) ----
  {
    const float4* gp = (const float4*)(p.ENCP8 + (((size_t)ab * 512 + asq * 128) << 9));
    float4* dp = (float4*)encpL;
    #pragma unroll
    for (int r = 0; r < 4; ++r) dp[tid + r * NT] = gp[tid + r * NT];
  }

  // ================= init =================
  #pragma unroll
  for (int rep = 0; rep < 2; ++rep) {
    int idx = rep * NT + tid;
    int b4 = idx >> 9, i = idx & 511;
    float v = p.hidden[(size_t)(bg * 4 + b4) * 512 + i];
    float vp = __shfl_xor(v, 1);
    if (!(i & 1)) hh2L[b4][i >> 1] = h2{(f16)v, (f16)vp};
  }
  if (rs == 0) {
    #pragma unroll
    for (int rep = 0; rep < 2; ++rep) {
      int idx = rep * NT + tid;
      int b4 = idx >> 9, i = idx & 511;
      xstf(p.HNEW + (size_t)(bg * 4 + b4) * 512 + i,
           p.hidden[(size_t)(bg * 4 + b4) * 512 + i]);
    }
  } else if (rs == 1) {
    if (tid < 512) {
      int b = bg * 4 + (tid >> 7), n = tid & 127;
      xstf(p.XF + b * 128 + n, p.dec_input[b * 128 + n]);
    }
  }
  __syncthreads();
  if (tid < 160) {
    int row = rs * 40 + (tid >> 2), b4 = tid & 3;
    if (row < 512) {
      const f16* wr = p.WA1 + (size_t)row * 512;
      float acc = 0.f;
      #pragma unroll 8
      for (int k4 = 0; k4 < 64; ++k4) {
        h8 hv = *(const h8*)&hh2L[b4][k4 * 4];
        h8 wv = *(const h8*)(wr + k4 * 8);
        const h2 *hq = (const h2*)&hv, *wq = (const h2*)&wv;
        #pragma unroll
        for (int e = 0; e < 4; ++e) acc = fdot2(hq[e], wq[e], acc);
      }
      xstf(p.HP + (size_t)(bg * 4 + b4) * 512 + row, 2.f * acc);
    }
  }
  groupbar(p.flags, ++ep);

  for (int step = 0; step < T_; ++step) {
    const int cur = step & 1, nxt = cur ^ 1;
    float* HNc = p.HNEW + cur * (64 * 512);
    float* HNn = p.HNEW + nxt * (64 * 512);

    // ================= A: scores + exp + c-partials over s-quarter =================
    if (tid < 512) {
      hpL[tid] = aldf(p.HP + (size_t)ab * 512 + tid);
    }
    __syncthreads();
    {
      float hp8[8];
      *(float4*)hp8 = *(const float4*)&hpL[lane * 8];
      *(float4*)(hp8 + 4) = *(const float4*)&hpL[lane * 8 + 4];
      const size_t sbase = (size_t)ab * 512 + asq * 128 + w * 8;
      // ENCP read from LDS (pinned); ENCF streamed with transient preload.
      const unsigned char* pbL = encpL + ((size_t)(w * 8) << 9) + lane * 8;
      const unsigned char* eb = p.ENCF8 + (sbase << 9) + lane * 8;
      u64 ev8[8];
      #pragma unroll
      for (int i = 0; i < 8; ++i)
        ev8[i] = *(const u64*)(eb + ((size_t)i << 9));
      float c8[8] = {};
      float den = 0.f;
      #pragma unroll
      for (int i = 0; i < 8; ++i) {
        u64 pv = *(const u64*)(pbL + ((size_t)i << 9));
        float pf[8], ef[8];
        fp8x8_to_f32(pv, pf);
        fp8x8_to_f32(ev8[i], ef);
        float acc = wvs;
        #pragma unroll
        for (int e = 0; e < 8; ++e) {
          float e2 = __expf(hp8[e] + pf[e]);                // e^{2x}
          acc += wv2[e] * __builtin_amdgcn_rcpf(e2 + 1.f);  // wv*(1 - 2/(1+e^2x))
        }
        #pragma unroll
        for (int off = 32; off; off >>= 1) acc += __shfl_xor(acc, off);
        float es = __expf(acc);                          // |score| <= ~11: safe
        den += es;
        #pragma unroll
        for (int e = 0; e < 8; ++e) c8[e] += es * ef[e];
      }
      #pragma unroll
      for (int e = 0; e < 8; ++e) cpart[w][e][lane] = c8[e];   // conflict-free
      if (lane == 0) dWL[w] = den;
    }
    __syncthreads();
    if (tid < 256) {
      int h0 = 2 * tid, h1 = 2 * tid + 1;
      float v0 = 0.f, v1 = 0.f;
      #pragma unroll
      for (int ww = 0; ww < 16; ++ww) {
        v0 += cpart[ww][h0 & 7][h0 >> 3];
        v1 += cpart[ww][h1 & 7][h1 >> 3];
      }
      xstu(p.CQ + (size_t)((ab << 2) | asq) * 256 + tid,
           packh2(v0 * 1.220703125e-4f, v1 * 1.220703125e-4f));   // x 2^-13
    } else if (tid == 256) {
      float d = 0.f;
      #pragma unroll
      for (int i = 0; i < 16; ++i) d += dWL[i];
      xstf(p.DEN + (ab << 2) + asq, d);
    }
    groupbar(p.flags, ++ep);

    // ================= B: gates + h update (4 batches x 32-h slice) =================
    if (tid < 4) {
      float s = 0.f;
      #pragma unroll
      for (int sq = 0; sq < 4; ++sq) s += aldf(p.DEN + ((bg * 4 + tid) << 2) + sq);
      invL[tid] = 8192.f * __builtin_amdgcn_rcpf(s);     // 2^13 / den
    }
    __syncthreads();
    {
      int b4 = tid >> 8, pp = tid & 255;
      float lo = 0.f, hi = 0.f;
      #pragma unroll
      for (int sq = 0; sq < 4; ++sq) {
        h2 v = unpackh2(aldu(p.CQ + (size_t)(((bg * 4 + b4) << 2) | sq) * 256 + pp));
        lo += (float)v[0]; hi += (float)v[1];
      }
      float inv = invL[b4];
      ch2L[b4][pp] = h2{(f16)(lo * inv), (f16)(hi * inv)};
    }
    #pragma unroll
    for (int rep = 0; rep < 2; ++rep) {
      int idx = rep * NT + tid;
      int b4 = idx >> 9, i = idx & 511;
      float v = aldf(HNc + (size_t)(bg * 4 + b4) * 512 + i);
      float vp = __shfl_xor(v, 1);
      if (!(i & 1)) hh2L[b4][i >> 1] = h2{(f16)v, (f16)vp};
      int d = i - hsb;
      if (d >= 0 && d < 32) hfL[b4][d] = v;
    }
    if (tid < 256) {
      int b4 = tid >> 6, n2 = (tid & 63) * 2;
      float x0 = aldf(p.XF + (bg * 4 + b4) * 128 + n2);
      float x1 = aldf(p.XF + (bg * 4 + b4) * 128 + n2 + 1);
      xh2L[b4][n2 >> 1] = h2{(f16)x0, (f16)x1};
    }
    __syncthreads();
    if (tid < 384) {
      int b4 = tid & 3, g = (tid >> 2) % 3, r = tid / 12;
      int j = g * 512 + hsb + r;
      const f16* wc = p.WC + (size_t)j * 512;
      const f16* wh = p.WHH + (size_t)j * 512;
      const f16* wx = p.WX + (size_t)j * 128;
      float gc = 0.f, gh = 0.f, gx = 0.f;
      #pragma unroll 4
      for (int k4 = 0; k4 < 64; ++k4) {
        h8 cv = *(const h8*)&ch2L[b4][k4 * 4];
        h8 hv = *(const h8*)&hh2L[b4][k4 * 4];
        h8 wcv = *(const h8*)(wc + k4 * 8);
        h8 whv = *(const h8*)(wh + k4 * 8);
        const h2 *cq = (const h2*)&cv, *hq = (const h2*)&hv;
        const h2 *wcq = (const h2*)&wcv, *whq = (const h2*)&whv;
        #pragma unroll
        for (int e = 0; e < 4; ++e) {
          gc = fdot2(cq[e], wcq[e], gc);
          gh = fdot2(hq[e], whq[e], gh);
        }
      }
      #pragma unroll
      for (int k4 = 0; k4 < 16; ++k4) {
        h8 xv = *(const h8*)&xh2L[b4][k4 * 4];
        h8 wxv = *(const h8*)(wx + k4 * 8);
        const h2 *xq = (const h2*)&xv, *wxq = (const h2*)&wxv;
        #pragma unroll
        for (int e = 0; e < 4; ++e) gx = fdot2(xq[e], wxq[e], gx);
      }
      g1L[tid] = gc + gx + p.bih[j];
      g2L[tid] = gh + p.bhh[j];
    }
    __syncthreads();
    if (tid < 128) {
      int b4 = tid & 3, r = tid >> 2;
      int i0 = r * 12 + b4;
      float rr = __builtin_amdgcn_rcpf(1.f + __expf(-(g1L[i0] + g2L[i0])));
      float zz = __builtin_amdgcn_rcpf(1.f + __expf(-(g1L[i0 + 4] + g2L[i0 + 4])));
      float narg = g1L[i0 + 8] + rr * g2L[i0 + 8];
      float nn = 1.f - 2.f * __builtin_amdgcn_rcpf(1.f + __expf(2.f * narg));
      float hn = (1.f - zz) * nn + zz * hfL[b4][r];
      xstf(HNn + (size_t)(bg * 4 + b4) * 512 + hsb + r, hn);
    }
    groupbar(p.flags, ++ep);

    // ================= C: hp, out, x from h_new =================
    #pragma unroll
    for (int rep = 0; rep < 2; ++rep) {
      int idx = rep * NT + tid;
      int b4 = idx >> 9, i = idx & 511;
      float v = aldf(HNn + (size_t)(bg * 4 + b4) * 512 + i);
      float vp = __shfl_xor(v, 1);
      if (!(i & 1)) hh2L[b4][i >> 1] = h2{(f16)v, (f16)vp};
    }
    __syncthreads();
    if (tid < 160) {
      int row = rs * 40 + (tid >> 2), b4 = tid & 3;
      const f16* wr = (row < 512) ? p.WA1 + (size_t)row * 512
                                  : p.WOUT + (size_t)(row - 512) * 512;
      float acc = 0.f;
      #pragma unroll 8
      for (int k4 = 0; k4 < 64; ++k4) {
        h8 hv = *(const h8*)&hh2L[b4][k4 * 4];
        h8 wv = *(const h8*)(wr + k4 * 8);
        const h2 *hq = (const h2*)&hv, *wq = (const h2*)&wv;
        #pragma unroll
        for (int e = 0; e < 4; ++e) acc = fdot2(hq[e], wq[e], acc);
      }
      int b = bg * 4 + b4;
      if (row < 512) {
        xstf(p.HP + (size_t)b * 512 + row, 2.f * acc);
      } else {
        int n = row - 512;
        float val = acc + p.bout[n];
        p.out[((size_t)b * T_ + step) * F_ + n] = val;
        xstf(p.XF + b * 128 + n, val);
      }
    }
    groupbar(p.flags, ++ep);
  }
}

extern "C" void kernel_launch(void* const* d_in, const int* in_sizes, int n_in,
                              void* d_out, int out_size, void* d_ws, size_t ws_size,
                              hipStream_t stream) {
  const float* dec_input = (const float*)d_in[0];
  const float* hidden    = (const float*)d_in[1];
  const float* enc       = (const float*)d_in[2];
  // d_in[3] expected_outputs, d_in[4] dec_output_len (fixed 96) unused
  const float* Wa   = (const float*)d_in[5];
  const float* ba   = (const float*)d_in[6];
  const float* Wv   = (const float*)d_in[7];
  // d_in[8] bv cancels in softmax
  const float* Wih  = (const float*)d_in[9];
  const float* bih  = (const float*)d_in[10];
  const float* Whh  = (const float*)d_in[11];
  const float* bhh  = (const float*)d_in[12];
  const float* Wout = (const float*)d_in[13];
  const float* bout = (const float*)d_in[14];

  char* ws = (char*)d_ws;
  f16* WTS  = (f16*)(ws + WTS_OFF);
  unsigned char* ENCP8 = (unsigned char*)(ws + ENCP8_OFF);
  unsigned char* ENCF8 = (unsigned char*)(ws + ENCF8_OFF);
  f16* ENCL = (f16*)(ws + ENCL_OFF);

  Params p;
  p.hidden = hidden; p.dec_input = dec_input; p.Wv = Wv;
  p.bih = bih; p.bhh = bhh; p.bout = bout;
  p.ENCP8 = ENCP8; p.ENCF8 = ENCF8;
  p.WA1 = WTS + WA1_E; p.WHH = WTS + WHH_E; p.WC = WTS + WC_E;
  p.WX = WTS + WX_E; p.WOUT = WTS + WOUT_E;
  p.HP = (float*)(ws + HP_OFF); p.XF = (float*)(ws + XF_OFF);
  p.DEN = (float*)(ws + DEN_OFF); p.HNEW = (float*)(ws + HNEW_OFF);
  p.CQ = (u32*)(ws + CQ_OFF);
  p.flags = (u32*)(ws + FLAG_OFF);
  p.out = (float*)d_out;

  hipMemsetAsync(ws, 0, 20480, stream);   // flag lines
  hipLaunchKernelGGL(transcode_enc, dim3(4096), dim3(256), 0, stream,
                     enc, ENCL, ENCF8);
  hipLaunchKernelGGL(pack_weights, dim3(9216), dim3(256), 0, stream,
                     Wa, Whh, Wih, Wout, WTS);
  hipLaunchKernelGGL(mfma_encproj, dim3(256, 4), dim3(256), 0, stream,
                     (const u16*)ENCL, (const u16*)(WTS + WA2_E), ba, ENCP8);

  void* args[] = {&p};
  hipLaunchCooperativeKernel((void*)decoder_phases, dim3(NB), dim3(NT), args,
                             65536, stream);
}